// Round 14
// baseline (245.036 us; speedup 1.0000x reference)
//
#include <hip/hip_runtime.h>
#include <float.h>
#include <limits.h>

// NearestCluster: per-batch NN argmin via uniform 8^3 grid (exact).
// *** R15 = DIAGNOSTIC ROUND ***: exact R9 structure (best: 82.2us bench,
// absmax 0), but both kernels repeat their full work x8 internally with
// bit-identical outputs, so both dispatches exceed the harness fill's ~40us
// and finally surface in the rocprof top-5 with real counters + timestamps.
// An opaque z0 (empty asm, +memory clobber per rep) defeats cross-rep load
// CSE so the measurement is honest (rule #17). R16 reverts kRep to 1.
//
// coords1 [L1=4096, N=8, C=3] f32 (reference), coords2 [L2=4096, N=8, C=3] f32 (query)
// out int32: [L2*N] argmin idx over L1 per batch, then [L2*N] batch idx.
//
// Numerics: bit-exact vs numpy f32 reference:
//   qq = (q0*q0 + q1*q1) + q2*q2         rr likewise (round each op, no fma)
//   dot = ((q0*r0) + (q1*r1)) + (q2*r2)
//   d2 = (qq + rr) - 2*dot  ==  fma(-2, dot, qq+rr)   (2*dot exact)
// Ties -> lowest ORIGINAL index; all updates/merges lexicographic on (d2, idx).
// cell = clamp(floor(x*8)): x*8 exact (pow2) -> pruning bound exact.
// Rep-loop safety: each bin rep rebuilds a complete, valid cell-ordered pts
// for its batch (within-cell order may permute across reps -- irrelevant, NN
// carries orig idx and is order-agnostic); each NN rep rewrites identical out.
//
// Pruning exactness (proven R7-R14): refs outside the 3^3 neighborhood have an
// axis gap > 1/8 => true d2 > lb = 0.015625 (exact). Computed-vs-true error
// <= ~3.6e-6; take the full-rescan fallback unless lb > bd + 4e-6 => pruned
// points' COMPUTED d2 > bd => never argmin nor tie. Empty neighborhood ->
// bd=FLT_MAX -> fallback fires (exact).
//
// ws layout (540928 B): int cellStart[8][520] | float4 pts[8][4096] (x,y,z,idx)
// Fallback to the verified R5 LDS brute-force kernel if ws too small.

constexpr int kL1 = 4096, kL2 = 4096, kN = 8;
constexpr int kCS = 520;
constexpr int kRep = 8;                                      // DIAGNOSTIC x8
constexpr size_t kOffPts = 8ull * kCS * 4;                   // 16640
constexpr size_t kWsBytes = kOffPts + 8ull * kL1 * 16;       // 540928

__device__ __forceinline__ float rr_exact(float x, float y, float z) {
  return __fadd_rn(__fadd_rn(__fmul_rn(x, x), __fmul_rn(y, y)), __fmul_rn(z, z));
}

// ---------------- Kernel 1: bin refs into 8^3 cells (R9 body, x8 rep) ----
__global__ __launch_bounds__(1024)
void bin_kernel(const float* __restrict__ c1, int* __restrict__ cellStart,
                float4* __restrict__ pts) {
#pragma clang fp contract(off)
  __shared__ int cnt[512];
  const int tid = threadIdx.x;
  const int n = blockIdx.x;

  for (int rep = 0; rep < kRep; ++rep) {
    int z0 = 0;
    asm volatile("" : "+v"(z0) :: "memory");   // opaque 0; no cross-rep CSE
    __syncthreads();                           // prior rep's scatter done
    if (tid < 512) cnt[tid] = 0;
    __syncthreads();

    float xs[4], ys[4], zs[4];
    int cl[4];
#pragma unroll
    for (int k = 0; k < 4; ++k) {
      const int j = k * 1024 + tid + z0;
      const float* p = c1 + (j * kN + n) * 3;
      const float x = p[0], y = p[1], z = p[2];
      xs[k] = x; ys[k] = y; zs[k] = z;
      const int cx = min(7, max(0, (int)(x * 8.0f)));
      const int cy = min(7, max(0, (int)(y * 8.0f)));
      const int cz = min(7, max(0, (int)(z * 8.0f)));
      cl[k] = (cz * 8 + cy) * 8 + cx;
      atomicAdd(&cnt[cl[k]], 1);
    }
    __syncthreads();

    // Exclusive prefix over 512 counts: wave 0, 8 cells/lane + shfl scan.
    if (tid < 64) {
      int loc[8], part = 0;
#pragma unroll
      for (int i = 0; i < 8; ++i) { loc[i] = cnt[tid * 8 + i]; part += loc[i]; }
      int inc = part;
#pragma unroll
      for (int off = 1; off < 64; off <<= 1) {
        const int v = __shfl_up(inc, off);
        if (tid >= off) inc += v;
      }
      int base = inc - part;
#pragma unroll
      for (int i = 0; i < 8; ++i) {
        const int c = tid * 8 + i;
        cellStart[n * kCS + c] = base;
        cnt[c] = base;               // becomes scatter cursor
        base += loc[i];
      }
      if (tid == 0) cellStart[n * kCS + 512] = kL1;
    }
    __syncthreads();

#pragma unroll
    for (int k = 0; k < 4; ++k) {
      const int j = k * 1024 + tid;
      const int pos = atomicAdd(&cnt[cl[k]], 1);
      pts[n * kL1 + pos] = make_float4(xs[k], ys[k], zs[k], __int_as_float(j));
    }
  }
}

// ---- Kernel 2: NN (exact R9 body: 8192 blocks, 1 query/wave), x8 rep ----
__global__ __launch_bounds__(256, 6)
void grid_nn_kernel(const int* __restrict__ cellStart, const float4* __restrict__ pts,
                    const float* __restrict__ c2, int* __restrict__ out) {
#pragma clang fp contract(off)
  const int n = blockIdx.y;
  const int wave = threadIdx.x >> 6;
  const int lane = threadIdx.x & 63;
  const int qj = blockIdx.x * 4 + wave;

  for (int rep = 0; rep < kRep; ++rep) {
    int z0 = 0;
    asm volatile("" : "+v"(z0) :: "memory");   // opaque 0; no cross-rep CSE

    const float* p = c2 + ((qj + z0) * kN + n) * 3;
    const float qx = p[0], qy = p[1], qz = p[2];
    const float qq = rr_exact(qx, qy, qz);
    const int cx = min(7, max(0, (int)(qx * 8.0f)));
    const int cy = min(7, max(0, (int)(qy * 8.0f)));
    const int cz = min(7, max(0, (int)(qz * 8.0f)));
    const int xlo = max(0, cx - 1), xhi = min(7, cx + 1);

    const int* __restrict__ cs = cellStart + n * kCS;
    const float4* __restrict__ P = pts + n * kL1 + z0;

    int S[9], Lk[9], pre[10];
#pragma unroll
    for (int k = 0; k < 9; ++k) {
      const int dz = k / 3 - 1, dy = k % 3 - 1;
      const int z = cz + dz, y = cy + dy;
      const bool valid = ((unsigned)z <= 7u) && ((unsigned)y <= 7u);
      const int zc = min(7, max(0, z)), yc = min(7, max(0, y));
      const int row = (zc * 8 + yc) * 8;
      const int s = cs[row + xlo];
      const int e = cs[row + xhi + 1];
      S[k] = s;
      Lk[k] = valid ? (e - s) : 0;
    }
    pre[0] = 0;
#pragma unroll
    for (int k = 0; k < 9; ++k) pre[k + 1] = pre[k] + Lk[k];
    const int T = pre[9];                      // wave-uniform

    float bd = FLT_MAX;
    int bi = INT_MAX;

    for (int base = 0; base < T; base += 256) {
      int gg[4], a[4];
#pragma unroll
      for (int u = 0; u < 4; ++u) {
        gg[u] = base + lane + u * 64;
        int ad = 0;
#pragma unroll
        for (int k = 0; k < 9; ++k) {
          const bool in = (gg[u] >= pre[k]) && (gg[u] < pre[k + 1]);
          ad = in ? (S[k] + (gg[u] - pre[k])) : ad;
        }
        a[u] = ad;
      }
      float4 rp[4];
#pragma unroll
      for (int u = 0; u < 4; ++u) rp[u] = P[a[u]];
#pragma unroll
      for (int u = 0; u < 4; ++u) {
        const int id = __float_as_int(rp[u].w);
        const float rr = rr_exact(rp[u].x, rp[u].y, rp[u].z);
        const float dot = __fadd_rn(
            __fadd_rn(__fmul_rn(qx, rp[u].x), __fmul_rn(qy, rp[u].y)),
            __fmul_rn(qz, rp[u].z));
        const float d2 = __fmaf_rn(-2.0f, dot, __fadd_rn(qq, rr));
        if (gg[u] < T && (d2 < bd || (d2 == bd && id < bi))) { bd = d2; bi = id; }
      }
    }

#pragma unroll
    for (int m = 1; m <= 32; m <<= 1) {
      const float od = __shfl_xor(bd, m);
      const int oi = __shfl_xor(bi, m);
      if (od < bd || (od == bd && oi < bi)) { bd = od; bi = oi; }
    }

    if (!(0.015625f > __fadd_rn(bd, 4e-6f))) {  // rare: full exact rescan
      for (int pp = lane; pp < kL1; pp += 64) {
        const float4 rp = P[pp];
        const int id = __float_as_int(rp.w);
        const float rr = rr_exact(rp.x, rp.y, rp.z);
        const float dot = __fadd_rn(
            __fadd_rn(__fmul_rn(qx, rp.x), __fmul_rn(qy, rp.y)),
            __fmul_rn(qz, rp.z));
        const float d2 = __fmaf_rn(-2.0f, dot, __fadd_rn(qq, rr));
        if (d2 < bd || (d2 == bd && id < bi)) { bd = d2; bi = id; }
      }
#pragma unroll
      for (int m = 1; m <= 32; m <<= 1) {
        const float od = __shfl_xor(bd, m);
        const int oi = __shfl_xor(bi, m);
        if (od < bd || (od == bd && oi < bi)) { bd = od; bi = oi; }
      }
    }

    if (lane == 0) {
      out[qj * kN + n] = bi;
      out[kL2 * kN + qj * kN + n] = n;
    }
  }
}

// ---------------- Fallback (verified R5/R6 brute force, LDS) ----------------
constexpr int kQPerBlock = 16;
constexpr int kQ = 4;
constexpr int kChunk = 1024;

__global__ __launch_bounds__(256, 4)
void nearest_kernel_lds(const float* __restrict__ c1, const float* __restrict__ c2,
                        int* __restrict__ out) {
#pragma clang fp contract(off)
  __shared__ float sRx[kChunk], sRy[kChunk], sRz[kChunk], sRr[kChunk];
  const int tid = threadIdx.x;
  const int n = blockIdx.y;
  const int wave = tid >> 6;
  const int lane = tid & 63;
  const int q0 = blockIdx.x * kQPerBlock + wave * kQ;

  float qxs[kQ], qys[kQ], qzs[kQ], qqs[kQ];
#pragma unroll
  for (int i = 0; i < kQ; ++i) {
    const float* p = c2 + ((q0 + i) * kN + n) * 3;
    qxs[i] = p[0]; qys[i] = p[1]; qzs[i] = p[2];
    qqs[i] = rr_exact(qxs[i], qys[i], qzs[i]);
  }
  float bd[kQ]; int bt[kQ];
#pragma unroll
  for (int i = 0; i < kQ; ++i) { bd[i] = FLT_MAX; bt[i] = 0; }

  for (int chunk = 0; chunk < kL1 / kChunk; ++chunk) {
    __syncthreads();
    {
      const int jb = chunk * kChunk + tid * 4;
      float x[4], y[4], z[4], w4[4];
#pragma unroll
      for (int k = 0; k < 4; ++k) {
        const float* p = c1 + ((jb + k) * kN + n) * 3;
        x[k] = p[0]; y[k] = p[1]; z[k] = p[2];
        w4[k] = rr_exact(x[k], y[k], z[k]);
      }
      *reinterpret_cast<float4*>(&sRx[tid * 4]) = make_float4(x[0], x[1], x[2], x[3]);
      *reinterpret_cast<float4*>(&sRy[tid * 4]) = make_float4(y[0], y[1], y[2], y[3]);
      *reinterpret_cast<float4*>(&sRz[tid * 4]) = make_float4(z[0], z[1], z[2], z[3]);
      *reinterpret_cast<float4*>(&sRr[tid * 4]) = make_float4(w4[0], w4[1], w4[2], w4[3]);
    }
    __syncthreads();
#pragma unroll
    for (int t = 0; t < kChunk / 256; ++t) {
      const int tg = chunk * (kChunk / 256) + t;
      const int base = t * 256 + lane * 4;
      const float4 x4 = *reinterpret_cast<const float4*>(&sRx[base]);
      const float4 y4 = *reinterpret_cast<const float4*>(&sRy[base]);
      const float4 z4 = *reinterpret_cast<const float4*>(&sRz[base]);
      const float4 r4 = *reinterpret_cast<const float4*>(&sRr[base]);
      const float xs[4] = {x4.x, x4.y, x4.z, x4.w};
      const float ys[4] = {y4.x, y4.y, y4.z, y4.w};
      const float zs[4] = {z4.x, z4.y, z4.z, z4.w};
      const float rs[4] = {r4.x, r4.y, r4.z, r4.w};
#pragma unroll
      for (int i = 0; i < kQ; ++i) {
        float d[4];
#pragma unroll
        for (int k = 0; k < 4; ++k) {
          const float dot = __fadd_rn(
              __fadd_rn(__fmul_rn(qxs[i], xs[k]), __fmul_rn(qys[i], ys[k])),
              __fmul_rn(qzs[i], zs[k]));
          d[k] = __fmaf_rn(-2.0f, dot, __fadd_rn(qqs[i], rs[k]));
        }
        const float old = bd[i];
        float m = fminf(fminf(d[0], d[1]), old);
        m = fminf(fminf(d[2], d[3]), m);
        bd[i] = m;
        if (m < old) bt[i] = tg;
      }
    }
  }
  int sel[kQ];
#pragma unroll
  for (int i = 0; i < kQ; ++i) sel[i] = bt[i] * 64 + lane;
#pragma unroll
  for (int m = 1; m <= 32; m <<= 1) {
#pragma unroll
    for (int i = 0; i < kQ; ++i) {
      const float od = __shfl_xor(bd[i], m);
      const int os = __shfl_xor(sel[i], m);
      if (od < bd[i] || (od == bd[i] && os < sel[i])) { bd[i] = od; sel[i] = os; }
    }
  }
#pragma unroll
  for (int i = 0; i < kQ; ++i) {
    if (lane == i) {
      const int j0 = sel[i] * 4;
      float best = FLT_MAX; int kk = 0;
#pragma unroll
      for (int k = 0; k < 4; ++k) {
        const float* p = c1 + ((j0 + k) * kN + n) * 3;
        const float r0 = p[0], r1 = p[1], r2 = p[2];
        const float rr = rr_exact(r0, r1, r2);
        const float dot = __fadd_rn(
            __fadd_rn(__fmul_rn(qxs[i], r0), __fmul_rn(qys[i], r1)),
            __fmul_rn(qzs[i], r2));
        const float dc = __fmaf_rn(-2.0f, dot, __fadd_rn(qqs[i], rr));
        if (dc < best) { best = dc; kk = k; }
      }
      out[(q0 + i) * kN + n] = j0 + kk;
      out[kL2 * kN + (q0 + i) * kN + n] = n;
    }
  }
}

extern "C" void kernel_launch(void* const* d_in, const int* in_sizes, int n_in,
                              void* d_out, int out_size, void* d_ws, size_t ws_size,
                              hipStream_t stream) {
  const float* c1 = (const float*)d_in[0];
  const float* c2 = (const float*)d_in[1];
  int* out = (int*)d_out;
  if (d_ws != nullptr && ws_size >= kWsBytes) {
    int* cellStart = (int*)d_ws;
    float4* pts = (float4*)((char*)d_ws + kOffPts);
    bin_kernel<<<dim3(kN), dim3(1024), 0, stream>>>(c1, cellStart, pts);
    grid_nn_kernel<<<dim3(kL2 / 4, kN), dim3(256), 0, stream>>>(
        cellStart, pts, c2, out);
  } else {
    dim3 grid(kL2 / kQPerBlock, kN);
    nearest_kernel_lds<<<grid, dim3(256), 0, stream>>>(c1, c2, out);
  }
}

// Round 15
// 91.900 us; speedup vs baseline: 2.6663x; 2.6663x over previous
//
#include <hip/hip_runtime.h>
#include <float.h>
#include <limits.h>

// NearestCluster: per-batch NN argmin via uniform 8^3 grid (exact), with
// MATERIALIZED per-cell neighbor candidate lists.
// coords1 [L1=4096, N=8, C=3] f32 (reference), coords2 [L2=4096, N=8, C=3] f32 (query)
// out int32: [L2*N] argmin idx over L1 per batch, then [L2*N] batch idx.
//
// R15 DIAGNOSTIC RESULT (x8 rep, real counters at last): grid_nn = 21.9us/rep,
// VALUBusy ~110% (saturated), Occupancy 70%, FETCH 2.4MB, conflicts 0 ->
// PURE VALU-ISSUE-BOUND. The R9 branch-free slot->address decode (9-section
// cndmask chain) is ~27 of ~40 issue slots per candidate. R16 removes it:
// an expansion kernel materializes each cell's 3^3-neighborhood candidates
// into contiguous (x,y,z,rr) + idx arrays (rr precomputed once); the NN
// kernel streams them with ZERO decode: ~120 slots/query-wave vs ~380.
//
// Numerics: bit-exact vs numpy f32 reference:
//   qq = (q0*q0 + q1*q1) + q2*q2         rr likewise (round each op, no fma)
//   dot = ((q0*r0) + (q1*r1)) + (q2*r2)
//   d2 = (qq + rr) - 2*dot  ==  fma(-2, dot, qq+rr)   (2*dot exact)
// rr precomputed in expansion uses the same exact chain on the same bits ->
// identical values. Ties -> lowest ORIGINAL index: candidates carry orig idx;
// every update/merge lexicographic on (d2, idx) -> list order irrelevant.
// Padding gaps between cells hold poison: updates guarded by slot<T (NaN-safe
// either way since NaN compares false). T=0 -> bd=FLT_MAX -> fallback.
//
// Pruning exactness (proven R7-R15): refs outside the 3^3 neighborhood have an
// axis gap > 1/8 => true d2 > lb = 0.015625 (exact). Computed-vs-true error
// <= ~3.6e-6; take the full-rescan fallback unless lb > bd + 4e-6 => pruned
// points' COMPUTED d2 > bd => never argmin nor tie. Fallback rescans all 4096
// cell-ordered refs (pts4 rr + pidx) -> exact in all cases.
//
// ws layout (18727424 B; harness ws ~268 MB):
//   csR int[8][520] | nbrStart int[8][520] (4-aligned starts) |
//   nbrLen int[8][512] | pidx int[8][4096] | pts4 f4[8][4096] (x,y,z,rr) |
//   nbrIdx int[8][112640] | nbrPts f4[8][112640]
// Bound: sum of padded T <= 27*4096 + 512*3 = 112128 <= 112640-256 overread pad.
// Fallback to the verified R5 LDS brute-force kernel if ws too small.

constexpr int kL1 = 4096, kL2 = 4096, kN = 8;
constexpr int kCS = 520;
constexpr int kNbrCap = 112640;
constexpr size_t kOffNbrStart = 8ull * kCS * 4;               // 16640
constexpr size_t kOffNbrLen = kOffNbrStart + 8ull * kCS * 4;  // 33280
constexpr size_t kOffPidx = kOffNbrLen + 8ull * 512 * 4;      // 49664
constexpr size_t kOffPts4 = kOffPidx + 8ull * kL1 * 4;        // 180736
constexpr size_t kOffNbrIdx = kOffPts4 + 8ull * kL1 * 16;     // 705024
constexpr size_t kOffNbrPts = kOffNbrIdx + 8ull * kNbrCap * 4;  // 4309504
constexpr size_t kWsBytes = kOffNbrPts + 8ull * kNbrCap * 16;   // 18727424

__device__ __forceinline__ float rr_exact(float x, float y, float z) {
  return __fadd_rn(__fadd_rn(__fmul_rn(x, x), __fmul_rn(y, y)), __fmul_rn(z, z));
}

// ---- K1: bin refs; compute cellStart, scatter pts4(x,y,z,rr)+pidx, and the
//      per-cell neighborhood lengths T -> aligned nbrStart + nbrLen ----
__global__ __launch_bounds__(1024)
void bin_kernel(const float* __restrict__ c1, int* __restrict__ cellStart,
                int* __restrict__ nbrStart, int* __restrict__ nbrLen,
                float4* __restrict__ pts4, int* __restrict__ pidx) {
#pragma clang fp contract(off)
  __shared__ int cnt[512];
  __shared__ int st[513];
  const int tid = threadIdx.x;
  const int n = blockIdx.x;
  if (tid < 512) cnt[tid] = 0;
  __syncthreads();

  float xs[4], ys[4], zs[4];
  int cl[4];
#pragma unroll
  for (int k = 0; k < 4; ++k) {
    const int j = k * 1024 + tid;
    const float* p = c1 + (j * kN + n) * 3;
    const float x = p[0], y = p[1], z = p[2];
    xs[k] = x; ys[k] = y; zs[k] = z;
    const int cx = min(7, max(0, (int)(x * 8.0f)));
    const int cy = min(7, max(0, (int)(y * 8.0f)));
    const int cz = min(7, max(0, (int)(z * 8.0f)));
    cl[k] = (cz * 8 + cy) * 8 + cx;
    atomicAdd(&cnt[cl[k]], 1);
  }
  __syncthreads();

  if (tid < 64) {  // exclusive scan of counts (R9-proven)
    int loc[8], part = 0;
#pragma unroll
    for (int i = 0; i < 8; ++i) { loc[i] = cnt[tid * 8 + i]; part += loc[i]; }
    int inc = part;
#pragma unroll
    for (int off = 1; off < 64; off <<= 1) {
      const int v = __shfl_up(inc, off);
      if (tid >= off) inc += v;
    }
    int base = inc - part;
#pragma unroll
    for (int i = 0; i < 8; ++i) {
      const int c = tid * 8 + i;
      cellStart[n * kCS + c] = base;
      st[c] = base;
      cnt[c] = base;                 // becomes scatter cursor
      base += loc[i];
    }
    if (tid == 0) { cellStart[n * kCS + 512] = kL1; st[512] = kL1; }
  }
  __syncthreads();

#pragma unroll
  for (int k = 0; k < 4; ++k) {
    const int j = k * 1024 + tid;
    const int pos = atomicAdd(&cnt[cl[k]], 1);
    pts4[n * kL1 + pos] =
        make_float4(xs[k], ys[k], zs[k], rr_exact(xs[k], ys[k], zs[k]));
    pidx[n * kL1 + pos] = j;
  }
  __syncthreads();

  // ---- per-cell neighborhood length T from st[] ----
  int Tc = 0;
  if (tid < 512) {
    const int cx = tid & 7, cy = (tid >> 3) & 7, cz = tid >> 6;
    const int xlo = max(0, cx - 1), xhi = min(7, cx + 1);
#pragma unroll
    for (int k = 0; k < 9; ++k) {
      const int dz = k / 3 - 1, dy = k % 3 - 1;
      const int z = cz + dz, y = cy + dy;
      if (((unsigned)z <= 7u) && ((unsigned)y <= 7u)) {
        const int row = (z * 8 + y) * 8;
        Tc += st[row + xhi + 1] - st[row + xlo];
      }
    }
  }
  __syncthreads();                   // scatter done; cnt reusable
  if (tid < 512) cnt[tid] = Tc;
  __syncthreads();

  if (tid < 64) {  // exclusive scan of 4-aligned T -> nbrStart; store nbrLen
    int loc[8], pad[8], part = 0;
#pragma unroll
    for (int i = 0; i < 8; ++i) {
      loc[i] = cnt[tid * 8 + i];
      pad[i] = (loc[i] + 3) & ~3;
      part += pad[i];
    }
    int inc = part;
#pragma unroll
    for (int off = 1; off < 64; off <<= 1) {
      const int v = __shfl_up(inc, off);
      if (tid >= off) inc += v;
    }
    int base = inc - part;
#pragma unroll
    for (int i = 0; i < 8; ++i) {
      const int c = tid * 8 + i;
      nbrStart[n * kCS + c] = base;
      nbrLen[n * 512 + c] = loc[i];
      base += pad[i];
    }
  }
}

// ---- K2: materialize neighbor lists; one wave per (batch, cell) ----
__global__ __launch_bounds__(256)
void expand_kernel(const int* __restrict__ cellStart, const int* __restrict__ nbrStart,
                   const float4* __restrict__ pts4, const int* __restrict__ pidx,
                   float4* __restrict__ nbrPts, int* __restrict__ nbrIdx) {
  const int wg = blockIdx.x * 4 + (threadIdx.x >> 6);   // 0..4095
  const int lane = threadIdx.x & 63;
  const int n = wg & 7, cell = wg >> 3;
  const int cx = cell & 7, cy = (cell >> 3) & 7, cz = cell >> 6;
  const int xlo = max(0, cx - 1), xhi = min(7, cx + 1);
  const int* __restrict__ cs = cellStart + n * kCS;
  const float4* __restrict__ P = pts4 + n * kL1;
  const int* __restrict__ I = pidx + n * kL1;
  const int d0 = nbrStart[n * kCS + cell];
  float4* __restrict__ DP = nbrPts + (size_t)n * kNbrCap + d0;
  int* __restrict__ DI = nbrIdx + (size_t)n * kNbrCap + d0;

  int dst = 0;
#pragma unroll
  for (int k = 0; k < 9; ++k) {
    const int dz = k / 3 - 1, dy = k % 3 - 1;
    const int z = cz + dz, y = cy + dy;
    if (((unsigned)z <= 7u) && ((unsigned)y <= 7u)) {
      const int row = (z * 8 + y) * 8;
      const int s = cs[row + xlo];
      const int len = cs[row + xhi + 1] - s;
      for (int i = lane; i < len; i += 64) {
        DP[dst + i] = P[s + i];
        DI[dst + i] = I[s + i];
      }
      dst += len;
    }
  }
}

// ---- K3: NN — stream the materialized list, zero decode (R9 grid shape) ----
__global__ __launch_bounds__(256, 6)
void grid_nn_kernel(const int* __restrict__ nbrStart, const int* __restrict__ nbrLen,
                    const float4* __restrict__ nbrPts, const int* __restrict__ nbrIdx,
                    const float4* __restrict__ pts4, const int* __restrict__ pidx,
                    const float* __restrict__ c2, int* __restrict__ out) {
#pragma clang fp contract(off)
  const int n = blockIdx.y;
  const int wave = threadIdx.x >> 6;
  const int lane = threadIdx.x & 63;
  const int qj = blockIdx.x * 4 + wave;

  const float* p = c2 + (qj * kN + n) * 3;     // same addr all lanes: broadcast
  const float qx = p[0], qy = p[1], qz = p[2];
  const float qq = rr_exact(qx, qy, qz);
  const int cx = min(7, max(0, (int)(qx * 8.0f)));
  const int cy = min(7, max(0, (int)(qy * 8.0f)));
  const int cz = min(7, max(0, (int)(qz * 8.0f)));
  const int cell = (cz * 8 + cy) * 8 + cx;

  const int start = nbrStart[n * kCS + cell];  // 4-aligned by construction
  const int T = nbrLen[n * 512 + cell];
  const float4* __restrict__ CP = nbrPts + (size_t)n * kNbrCap + start;
  const int* __restrict__ CI = nbrIdx + (size_t)n * kNbrCap + start;

  float bd = FLT_MAX;
  int bi = INT_MAX;

  for (int base = 0; base < T; base += 256) {  // 1 trip typ. (T ~ 216)
    const int s0 = base + lane * 4;
    const int4 id4 = *reinterpret_cast<const int4*>(CI + s0);  // 16B-aligned
    const int idv[4] = {id4.x, id4.y, id4.z, id4.w};
    float4 rp[4];
#pragma unroll
    for (int u = 0; u < 4; ++u) rp[u] = CP[s0 + u];
#pragma unroll
    for (int u = 0; u < 4; ++u) {
      const float dot = __fadd_rn(
          __fadd_rn(__fmul_rn(qx, rp[u].x), __fmul_rn(qy, rp[u].y)),
          __fmul_rn(qz, rp[u].z));
      const float d2 = __fmaf_rn(-2.0f, dot, __fadd_rn(qq, rp[u].w));
      if (s0 + u < T && (d2 < bd || (d2 == bd && idv[u] < bi))) {
        bd = d2; bi = idv[u];
      }
    }
  }

  // Merge across the wave (lexicographic on (d2, idx)).
#pragma unroll
  for (int m = 1; m <= 32; m <<= 1) {
    const float od = __shfl_xor(bd, m);
    const int oi = __shfl_xor(bi, m);
    if (od < bd || (od == bd && oi < bi)) { bd = od; bi = oi; }
  }

  // Fallback (wave-uniform, astronomically rare; also T=0): full exact rescan.
  if (!(0.015625f > __fadd_rn(bd, 4e-6f))) {
    const float4* __restrict__ P = pts4 + n * kL1;
    const int* __restrict__ I = pidx + n * kL1;
    for (int pp = lane; pp < kL1; pp += 64) {
      const float4 rp = P[pp];
      const int id = I[pp];
      const float dot = __fadd_rn(
          __fadd_rn(__fmul_rn(qx, rp.x), __fmul_rn(qy, rp.y)),
          __fmul_rn(qz, rp.z));
      const float d2 = __fmaf_rn(-2.0f, dot, __fadd_rn(qq, rp.w));
      if (d2 < bd || (d2 == bd && id < bi)) { bd = d2; bi = id; }
    }
#pragma unroll
    for (int m = 1; m <= 32; m <<= 1) {
      const float od = __shfl_xor(bd, m);
      const int oi = __shfl_xor(bi, m);
      if (od < bd || (od == bd && oi < bi)) { bd = od; bi = oi; }
    }
  }

  if (lane == 0) {
    out[qj * kN + n] = bi;
    out[kL2 * kN + qj * kN + n] = n;
  }
}

// ---------------- Fallback (verified R5/R6 brute force, LDS) ----------------
constexpr int kQPerBlock = 16;
constexpr int kQ = 4;
constexpr int kChunk = 1024;

__global__ __launch_bounds__(256, 4)
void nearest_kernel_lds(const float* __restrict__ c1, const float* __restrict__ c2,
                        int* __restrict__ out) {
#pragma clang fp contract(off)
  __shared__ float sRx[kChunk], sRy[kChunk], sRz[kChunk], sRr[kChunk];
  const int tid = threadIdx.x;
  const int n = blockIdx.y;
  const int wave = tid >> 6;
  const int lane = tid & 63;
  const int q0 = blockIdx.x * kQPerBlock + wave * kQ;

  float qxs[kQ], qys[kQ], qzs[kQ], qqs[kQ];
#pragma unroll
  for (int i = 0; i < kQ; ++i) {
    const float* p = c2 + ((q0 + i) * kN + n) * 3;
    qxs[i] = p[0]; qys[i] = p[1]; qzs[i] = p[2];
    qqs[i] = rr_exact(qxs[i], qys[i], qzs[i]);
  }
  float bd[kQ]; int bt[kQ];
#pragma unroll
  for (int i = 0; i < kQ; ++i) { bd[i] = FLT_MAX; bt[i] = 0; }

  for (int chunk = 0; chunk < kL1 / kChunk; ++chunk) {
    __syncthreads();
    {
      const int jb = chunk * kChunk + tid * 4;
      float x[4], y[4], z[4], w4[4];
#pragma unroll
      for (int k = 0; k < 4; ++k) {
        const float* p = c1 + ((jb + k) * kN + n) * 3;
        x[k] = p[0]; y[k] = p[1]; z[k] = p[2];
        w4[k] = rr_exact(x[k], y[k], z[k]);
      }
      *reinterpret_cast<float4*>(&sRx[tid * 4]) = make_float4(x[0], x[1], x[2], x[3]);
      *reinterpret_cast<float4*>(&sRy[tid * 4]) = make_float4(y[0], y[1], y[2], y[3]);
      *reinterpret_cast<float4*>(&sRz[tid * 4]) = make_float4(z[0], z[1], z[2], z[3]);
      *reinterpret_cast<float4*>(&sRr[tid * 4]) = make_float4(w4[0], w4[1], w4[2], w4[3]);
    }
    __syncthreads();
#pragma unroll
    for (int t = 0; t < kChunk / 256; ++t) {
      const int tg = chunk * (kChunk / 256) + t;
      const int base = t * 256 + lane * 4;
      const float4 x4 = *reinterpret_cast<const float4*>(&sRx[base]);
      const float4 y4 = *reinterpret_cast<const float4*>(&sRy[base]);
      const float4 z4 = *reinterpret_cast<const float4*>(&sRz[base]);
      const float4 r4 = *reinterpret_cast<const float4*>(&sRr[base]);
      const float xs[4] = {x4.x, x4.y, x4.z, x4.w};
      const float ys[4] = {y4.x, y4.y, y4.z, y4.w};
      const float zs[4] = {z4.x, z4.y, z4.z, z4.w};
      const float rs[4] = {r4.x, r4.y, r4.z, r4.w};
#pragma unroll
      for (int i = 0; i < kQ; ++i) {
        float d[4];
#pragma unroll
        for (int k = 0; k < 4; ++k) {
          const float dot = __fadd_rn(
              __fadd_rn(__fmul_rn(qxs[i], xs[k]), __fmul_rn(qys[i], ys[k])),
              __fmul_rn(qzs[i], zs[k]));
          d[k] = __fmaf_rn(-2.0f, dot, __fadd_rn(qqs[i], rs[k]));
        }
        const float old = bd[i];
        float m = fminf(fminf(d[0], d[1]), old);
        m = fminf(fminf(d[2], d[3]), m);
        bd[i] = m;
        if (m < old) bt[i] = tg;
      }
    }
  }
  int sel[kQ];
#pragma unroll
  for (int i = 0; i < kQ; ++i) sel[i] = bt[i] * 64 + lane;
#pragma unroll
  for (int m = 1; m <= 32; m <<= 1) {
#pragma unroll
    for (int i = 0; i < kQ; ++i) {
      const float od = __shfl_xor(bd[i], m);
      const int os = __shfl_xor(sel[i], m);
      if (od < bd[i] || (od == bd[i] && os < sel[i])) { bd[i] = od; sel[i] = os; }
    }
  }
#pragma unroll
  for (int i = 0; i < kQ; ++i) {
    if (lane == i) {
      const int j0 = sel[i] * 4;
      float best = FLT_MAX; int kk = 0;
#pragma unroll
      for (int k = 0; k < 4; ++k) {
        const float* p = c1 + ((j0 + k) * kN + n) * 3;
        const float r0 = p[0], r1 = p[1], r2 = p[2];
        const float rr = rr_exact(r0, r1, r2);
        const float dot = __fadd_rn(
            __fadd_rn(__fmul_rn(qxs[i], r0), __fmul_rn(qys[i], r1)),
            __fmul_rn(qzs[i], r2));
        const float dc = __fmaf_rn(-2.0f, dot, __fadd_rn(qqs[i], rr));
        if (dc < best) { best = dc; kk = k; }
      }
      out[(q0 + i) * kN + n] = j0 + kk;
      out[kL2 * kN + (q0 + i) * kN + n] = n;
    }
  }
}

extern "C" void kernel_launch(void* const* d_in, const int* in_sizes, int n_in,
                              void* d_out, int out_size, void* d_ws, size_t ws_size,
                              hipStream_t stream) {
  const float* c1 = (const float*)d_in[0];
  const float* c2 = (const float*)d_in[1];
  int* out = (int*)d_out;
  if (d_ws != nullptr && ws_size >= kWsBytes) {
    int* cellStart = (int*)d_ws;
    int* nbrStart = (int*)((char*)d_ws + kOffNbrStart);
    int* nbrLen = (int*)((char*)d_ws + kOffNbrLen);
    int* pidx = (int*)((char*)d_ws + kOffPidx);
    float4* pts4 = (float4*)((char*)d_ws + kOffPts4);
    int* nbrIdx = (int*)((char*)d_ws + kOffNbrIdx);
    float4* nbrPts = (float4*)((char*)d_ws + kOffNbrPts);
    bin_kernel<<<dim3(kN), dim3(1024), 0, stream>>>(c1, cellStart, nbrStart,
                                                    nbrLen, pts4, pidx);
    expand_kernel<<<dim3(1024), dim3(256), 0, stream>>>(cellStart, nbrStart,
                                                        pts4, pidx, nbrPts, nbrIdx);
    grid_nn_kernel<<<dim3(kL2 / 4, kN), dim3(256), 0, stream>>>(
        nbrStart, nbrLen, nbrPts, nbrIdx, pts4, pidx, c2, out);
  } else {
    dim3 grid(kL2 / kQPerBlock, kN);
    nearest_kernel_lds<<<grid, dim3(256), 0, stream>>>(c1, c2, out);
  }
}

// Round 16
// 84.479 us; speedup vs baseline: 2.9005x; 1.0878x over previous
//
#include <hip/hip_runtime.h>
#include <float.h>
#include <limits.h>

// NearestCluster: per-batch NN argmin via uniform 8^3 grid (exact).
// coords1 [L1=4096, N=8, C=3] f32 (reference), coords2 [L2=4096, N=8, C=3] f32 (query)
// out int32: [L2*N] argmin idx over L1 per batch, then [L2*N] batch idx.
//
// R15 MEASURED (x8-rep counters): NN VALU-saturated, ~825 instr/query-wave,
// 21.9us; bin ~3us. The surplus over the ~250-instr floor is R9's per-slot
// branch-free decode (27 slots/candidate). R16 (materialized lists) removed
// the decode but paid more in expand+heavier-bin+extra-dispatch (91.9 bench).
// R17 removes the decode STRUCTURALLY, in place: hoisted branch-free 18
// cs-loads -> register section table S[9],L[9] (R9's latency fix), then 9
// unrolled sections iterated directly with P[S[k]+i] (R8's cheap iteration,
// 1 add/candidate, no decode). ~230 instr/wave -> NN ~6-8us predicted.
// Everything else (bin, grid shape, merge, fallback) is R9 verbatim.
//
// Numerics: bit-exact vs numpy f32 reference:
//   qq = (q0*q0 + q1*q1) + q2*q2         rr likewise (round each op, no fma)
//   dot = ((q0*r0) + (q1*r1)) + (q2*r2)
//   d2 = (qq + rr) - 2*dot  ==  fma(-2, dot, qq+rr)   (2*dot exact)
// Ties -> lowest ORIGINAL index: candidates carry orig idx in pts.w; every
// update and merge is lexicographic on (d2, idx) -> order irrelevant.
// cell = clamp(floor(x*8)): x*8 exact (pow2) -> pruning bound exact.
//
// Pruning exactness (proven R7-R16): refs outside the 3^3 neighborhood have an
// axis gap > 1/8 => true d2 > lb = 0.015625 (exact). Computed-vs-true error
// <= ~3.6e-6; take the full-rescan fallback unless lb > bd + 4e-6 => pruned
// points' COMPUTED d2 > bd => never argmin nor tie. Empty neighborhood ->
// bd=FLT_MAX -> fallback fires (exact full rescan, idx carried).
//
// ws layout (540928 B): int cellStart[8][520] | float4 pts[8][4096] (x,y,z,idx)
// Fallback to the verified R5 LDS brute-force kernel if ws too small.

constexpr int kL1 = 4096, kL2 = 4096, kN = 8;
constexpr int kCS = 520;
constexpr size_t kOffPts = 8ull * kCS * 4;                   // 16640
constexpr size_t kWsBytes = kOffPts + 8ull * kL1 * 16;       // 540928

__device__ __forceinline__ float rr_exact(float x, float y, float z) {
  return __fadd_rn(__fadd_rn(__fmul_rn(x, x), __fmul_rn(y, y)), __fmul_rn(z, z));
}

// ---------------- Kernel 1: bin refs into 8^3 cells per batch (R9 verbatim) ----
__global__ __launch_bounds__(1024)
void bin_kernel(const float* __restrict__ c1, int* __restrict__ cellStart,
                float4* __restrict__ pts) {
#pragma clang fp contract(off)
  __shared__ int cnt[512];
  const int tid = threadIdx.x;
  const int n = blockIdx.x;
  if (tid < 512) cnt[tid] = 0;
  __syncthreads();

  float xs[4], ys[4], zs[4];
  int cl[4];
#pragma unroll
  for (int k = 0; k < 4; ++k) {
    const int j = k * 1024 + tid;
    const float* p = c1 + (j * kN + n) * 3;
    const float x = p[0], y = p[1], z = p[2];
    xs[k] = x; ys[k] = y; zs[k] = z;
    const int cx = min(7, max(0, (int)(x * 8.0f)));
    const int cy = min(7, max(0, (int)(y * 8.0f)));
    const int cz = min(7, max(0, (int)(z * 8.0f)));
    cl[k] = (cz * 8 + cy) * 8 + cx;
    atomicAdd(&cnt[cl[k]], 1);
  }
  __syncthreads();

  // Exclusive prefix over 512 counts: wave 0, 8 cells/lane + shfl scan.
  if (tid < 64) {
    int loc[8], part = 0;
#pragma unroll
    for (int i = 0; i < 8; ++i) { loc[i] = cnt[tid * 8 + i]; part += loc[i]; }
    int inc = part;
#pragma unroll
    for (int off = 1; off < 64; off <<= 1) {
      const int v = __shfl_up(inc, off);
      if (tid >= off) inc += v;
    }
    int base = inc - part;
#pragma unroll
    for (int i = 0; i < 8; ++i) {
      const int c = tid * 8 + i;
      cellStart[n * kCS + c] = base;
      cnt[c] = base;                 // becomes scatter cursor
      base += loc[i];
    }
    if (tid == 0) cellStart[n * kCS + 512] = kL1;
  }
  __syncthreads();

#pragma unroll
  for (int k = 0; k < 4; ++k) {
    const int j = k * 1024 + tid;
    const int pos = atomicAdd(&cnt[cl[k]], 1);
    pts[n * kL1 + pos] = make_float4(xs[k], ys[k], zs[k], __int_as_float(j));
  }
}

// ---- Kernel 2: NN — hoisted section table + direct section iteration ----
__global__ __launch_bounds__(256, 6)
void grid_nn_kernel(const int* __restrict__ cellStart, const float4* __restrict__ pts,
                    const float* __restrict__ c2, int* __restrict__ out) {
#pragma clang fp contract(off)
  const int n = blockIdx.y;
  const int wave = threadIdx.x >> 6;
  const int lane = threadIdx.x & 63;
  const int qj = blockIdx.x * 4 + wave;

  const float* p = c2 + (qj * kN + n) * 3;     // same addr all lanes: broadcast
  const float qx = p[0], qy = p[1], qz = p[2];
  const float qq = rr_exact(qx, qy, qz);
  const int cx = min(7, max(0, (int)(qx * 8.0f)));
  const int cy = min(7, max(0, (int)(qy * 8.0f)));
  const int cz = min(7, max(0, (int)(qz * 8.0f)));
  const int xlo = max(0, cx - 1), xhi = min(7, cx + 1);

  const int* __restrict__ cs = cellStart + n * kCS;
  const float4* __restrict__ P = pts + n * kL1;

  // Hoisted branch-free section table: 18 independent cs loads in flight
  // (R9's latency fix). L[k]=0 disables invalid sections; no decode later.
  int S[9], L[9];
#pragma unroll
  for (int k = 0; k < 9; ++k) {
    const int dz = k / 3 - 1, dy = k % 3 - 1;
    const int z = cz + dz, y = cy + dy;
    const bool valid = ((unsigned)z <= 7u) && ((unsigned)y <= 7u);
    const int zc = min(7, max(0, z)), yc = min(7, max(0, y));
    const int row = (zc * 8 + yc) * 8;
    const int s = cs[row + xlo];
    const int e = cs[row + xhi + 1];
    S[k] = s;
    L[k] = valid ? (e - s) : 0;
  }

  float bd = FLT_MAX;
  int bi = INT_MAX;

  // Direct iteration: 1 add per candidate, no slot decode (R8's cheap loop,
  // now latency-safe because all section bounds are already in registers).
#pragma unroll
  for (int k = 0; k < 9; ++k) {
    for (int i = lane; i < L[k]; i += 64) {    // typ. 1 iter (~24 pts/section)
      const float4 rp = P[S[k] + i];
      const int id = __float_as_int(rp.w);
      const float rr = rr_exact(rp.x, rp.y, rp.z);
      const float dot = __fadd_rn(
          __fadd_rn(__fmul_rn(qx, rp.x), __fmul_rn(qy, rp.y)),
          __fmul_rn(qz, rp.z));
      const float d2 = __fmaf_rn(-2.0f, dot, __fadd_rn(qq, rr));
      if (d2 < bd || (d2 == bd && id < bi)) { bd = d2; bi = id; }
    }
  }

  // Merge across the wave (lexicographic on (d2, idx)).
#pragma unroll
  for (int m = 1; m <= 32; m <<= 1) {
    const float od = __shfl_xor(bd, m);
    const int oi = __shfl_xor(bi, m);
    if (od < bd || (od == bd && oi < bi)) { bd = od; bi = oi; }
  }

  // Fallback (wave-uniform, astronomically rare; also empty-neighborhood):
  // full exact rescan of all 4096 cell-ordered refs.
  if (!(0.015625f > __fadd_rn(bd, 4e-6f))) {
    for (int pp = lane; pp < kL1; pp += 64) {
      const float4 rp = P[pp];
      const int id = __float_as_int(rp.w);
      const float rr = rr_exact(rp.x, rp.y, rp.z);
      const float dot = __fadd_rn(
          __fadd_rn(__fmul_rn(qx, rp.x), __fmul_rn(qy, rp.y)),
          __fmul_rn(qz, rp.z));
      const float d2 = __fmaf_rn(-2.0f, dot, __fadd_rn(qq, rr));
      if (d2 < bd || (d2 == bd && id < bi)) { bd = d2; bi = id; }
    }
#pragma unroll
    for (int m = 1; m <= 32; m <<= 1) {
      const float od = __shfl_xor(bd, m);
      const int oi = __shfl_xor(bi, m);
      if (od < bd || (od == bd && oi < bi)) { bd = od; bi = oi; }
    }
  }

  if (lane == 0) {
    out[qj * kN + n] = bi;
    out[kL2 * kN + qj * kN + n] = n;
  }
}

// ---------------- Fallback (verified R5/R6 brute force, LDS) ----------------
constexpr int kQPerBlock = 16;
constexpr int kQ = 4;
constexpr int kChunk = 1024;

__global__ __launch_bounds__(256, 4)
void nearest_kernel_lds(const float* __restrict__ c1, const float* __restrict__ c2,
                        int* __restrict__ out) {
#pragma clang fp contract(off)
  __shared__ float sRx[kChunk], sRy[kChunk], sRz[kChunk], sRr[kChunk];
  const int tid = threadIdx.x;
  const int n = blockIdx.y;
  const int wave = tid >> 6;
  const int lane = tid & 63;
  const int q0 = blockIdx.x * kQPerBlock + wave * kQ;

  float qxs[kQ], qys[kQ], qzs[kQ], qqs[kQ];
#pragma unroll
  for (int i = 0; i < kQ; ++i) {
    const float* p = c2 + ((q0 + i) * kN + n) * 3;
    qxs[i] = p[0]; qys[i] = p[1]; qzs[i] = p[2];
    qqs[i] = rr_exact(qxs[i], qys[i], qzs[i]);
  }
  float bd[kQ]; int bt[kQ];
#pragma unroll
  for (int i = 0; i < kQ; ++i) { bd[i] = FLT_MAX; bt[i] = 0; }

  for (int chunk = 0; chunk < kL1 / kChunk; ++chunk) {
    __syncthreads();
    {
      const int jb = chunk * kChunk + tid * 4;
      float x[4], y[4], z[4], w4[4];
#pragma unroll
      for (int k = 0; k < 4; ++k) {
        const float* p = c1 + ((jb + k) * kN + n) * 3;
        x[k] = p[0]; y[k] = p[1]; z[k] = p[2];
        w4[k] = rr_exact(x[k], y[k], z[k]);
      }
      *reinterpret_cast<float4*>(&sRx[tid * 4]) = make_float4(x[0], x[1], x[2], x[3]);
      *reinterpret_cast<float4*>(&sRy[tid * 4]) = make_float4(y[0], y[1], y[2], y[3]);
      *reinterpret_cast<float4*>(&sRz[tid * 4]) = make_float4(z[0], z[1], z[2], z[3]);
      *reinterpret_cast<float4*>(&sRr[tid * 4]) = make_float4(w4[0], w4[1], w4[2], w4[3]);
    }
    __syncthreads();
#pragma unroll
    for (int t = 0; t < kChunk / 256; ++t) {
      const int tg = chunk * (kChunk / 256) + t;
      const int base = t * 256 + lane * 4;
      const float4 x4 = *reinterpret_cast<const float4*>(&sRx[base]);
      const float4 y4 = *reinterpret_cast<const float4*>(&sRy[base]);
      const float4 z4 = *reinterpret_cast<const float4*>(&sRz[base]);
      const float4 r4 = *reinterpret_cast<const float4*>(&sRr[base]);
      const float xs[4] = {x4.x, x4.y, x4.z, x4.w};
      const float ys[4] = {y4.x, y4.y, y4.z, y4.w};
      const float zs[4] = {z4.x, z4.y, z4.z, z4.w};
      const float rs[4] = {r4.x, r4.y, r4.z, r4.w};
#pragma unroll
      for (int i = 0; i < kQ; ++i) {
        float d[4];
#pragma unroll
        for (int k = 0; k < 4; ++k) {
          const float dot = __fadd_rn(
              __fadd_rn(__fmul_rn(qxs[i], xs[k]), __fmul_rn(qys[i], ys[k])),
              __fmul_rn(qzs[i], zs[k]));
          d[k] = __fmaf_rn(-2.0f, dot, __fadd_rn(qqs[i], rs[k]));
        }
        const float old = bd[i];
        float m = fminf(fminf(d[0], d[1]), old);
        m = fminf(fminf(d[2], d[3]), m);
        bd[i] = m;
        if (m < old) bt[i] = tg;
      }
    }
  }
  int sel[kQ];
#pragma unroll
  for (int i = 0; i < kQ; ++i) sel[i] = bt[i] * 64 + lane;
#pragma unroll
  for (int m = 1; m <= 32; m <<= 1) {
#pragma unroll
    for (int i = 0; i < kQ; ++i) {
      const float od = __shfl_xor(bd[i], m);
      const int os = __shfl_xor(sel[i], m);
      if (od < bd[i] || (od == bd[i] && os < sel[i])) { bd[i] = od; sel[i] = os; }
    }
  }
#pragma unroll
  for (int i = 0; i < kQ; ++i) {
    if (lane == i) {
      const int j0 = sel[i] * 4;
      float best = FLT_MAX; int kk = 0;
#pragma unroll
      for (int k = 0; k < 4; ++k) {
        const float* p = c1 + ((j0 + k) * kN + n) * 3;
        const float r0 = p[0], r1 = p[1], r2 = p[2];
        const float rr = rr_exact(r0, r1, r2);
        const float dot = __fadd_rn(
            __fadd_rn(__fmul_rn(qxs[i], r0), __fmul_rn(qys[i], r1)),
            __fmul_rn(qzs[i], r2));
        const float dc = __fmaf_rn(-2.0f, dot, __fadd_rn(qqs[i], rr));
        if (dc < best) { best = dc; kk = k; }
      }
      out[(q0 + i) * kN + n] = j0 + kk;
      out[kL2 * kN + (q0 + i) * kN + n] = n;
    }
  }
}

extern "C" void kernel_launch(void* const* d_in, const int* in_sizes, int n_in,
                              void* d_out, int out_size, void* d_ws, size_t ws_size,
                              hipStream_t stream) {
  const float* c1 = (const float*)d_in[0];
  const float* c2 = (const float*)d_in[1];
  int* out = (int*)d_out;
  if (d_ws != nullptr && ws_size >= kWsBytes) {
    int* cellStart = (int*)d_ws;
    float4* pts = (float4*)((char*)d_ws + kOffPts);
    bin_kernel<<<dim3(kN), dim3(1024), 0, stream>>>(c1, cellStart, pts);
    grid_nn_kernel<<<dim3(kL2 / 4, kN), dim3(256), 0, stream>>>(
        cellStart, pts, c2, out);
  } else {
    dim3 grid(kL2 / kQPerBlock, kN);
    nearest_kernel_lds<<<grid, dim3(256), 0, stream>>>(c1, c2, out);
  }
}